// Round 7
// baseline (193.139 us; speedup 1.0000x reference)
//
#include <hip/hip_runtime.h>

#define H_ 1024
#define NH_ 16
#define HD_ 64
#define B_ 2
#define S_ 2048
#define BS_ 4096

typedef _Float16 half8 __attribute__((ext_vector_type(8)));
typedef _Float16 half4_t __attribute__((ext_vector_type(4)));
typedef float floatx4 __attribute__((ext_vector_type(4)));

#define LOG2E 1.44269504088896f

__device__ __forceinline__ void async_copy16(void* lds, const void* g) {
  __builtin_amdgcn_global_load_lds(
      (const __attribute__((address_space(1))) unsigned int*)g,
      (__attribute__((address_space(3))) unsigned int*)lds, 16, 0, 0);
}

// ---------------- fp32 -> fp16 conversion (hs + 4 weights) ----------------
__global__ __launch_bounds__(256) void cvt_all(
    const float* __restrict__ hs, const float* __restrict__ wq,
    const float* __restrict__ wk, const float* __restrict__ wv,
    const float* __restrict__ wo,
    _Float16* __restrict__ hs_h, _Float16* __restrict__ w_h) {
  int i = blockIdx.x * 256 + threadIdx.x;
  int idx = i * 4;
  const float* src; _Float16* dst; int off;
  if (idx < BS_ * H_) {
    src = hs; dst = hs_h; off = idx;
  } else {
    int j = idx - BS_ * H_;
    int w = j >> 20;
    off = j & ((1 << 20) - 1);
    src = (w == 0) ? wq : (w == 1) ? wk : (w == 2) ? wv : wo;
    dst = w_h + (size_t)w * (H_ * H_);
  }
  float4 f = *(const float4*)(src + off);
  half4_t o;
  o.x = (_Float16)f.x; o.y = (_Float16)f.y;
  o.z = (_Float16)f.z; o.w = (_Float16)f.w;
  *(half4_t*)(dst + off) = o;
}

// ---------------- QKV GEMM: C = A @ W^T ------------------------------------
// grid (8, 32, 3) block 256. z: 0=q (elu+1, *log2e) 1=k (elu+1)
// 2=v -> v^T with per-128-key-tile PERMUTED storage: key k stored at
// t*32 + q*8 + w16*4 + j (t=k>>5, w16=(k>>4)&1, q=(k>>2)&3, j=k&3), so the
// flash kernel can read PV A-fragments as single b128s.
__global__ __launch_bounds__(256) void qkv_gemm(
    const _Float16* __restrict__ A, const _Float16* __restrict__ Wall,
    _Float16* __restrict__ qh, _Float16* __restrict__ kh,
    _Float16* __restrict__ vt) {
  const int z = blockIdx.z;
  const _Float16* W = Wall + (size_t)z * (H_ * H_);
  const int rbase = blockIdx.y * 128;
  const int cbase = blockIdx.x * 128;
  __shared__ _Float16 As[128 * 32];
  __shared__ _Float16 Bs[128 * 32];
  const int tid = threadIdx.x, lane = tid & 63, w = tid >> 6;
  const int quad = lane >> 4, l16 = lane & 15;
  const int wr = (w >> 1) * 64, wc = (w & 1) * 64;

  floatx4 zero = {0.f, 0.f, 0.f, 0.f};
  floatx4 acc[4][4];
#pragma unroll
  for (int i = 0; i < 4; ++i)
#pragma unroll
    for (int j = 0; j < 4; ++j) acc[i][j] = zero;

  const int srow = w * 32 + (lane >> 2);
  const int sseg = (lane & 3) * 8;
  const _Float16* Ag = A + (size_t)(rbase + srow) * H_ + sseg;
  const _Float16* Bg = W + (size_t)(cbase + srow) * H_ + sseg;

  for (int k0 = 0; k0 < H_; k0 += 32) {
    async_copy16(&As[(w * 32) * 32], Ag + k0);
    async_copy16(&As[(w * 32 + 16) * 32], Ag + 16 * H_ + k0);
    async_copy16(&Bs[(w * 32) * 32], Bg + k0);
    async_copy16(&Bs[(w * 32 + 16) * 32], Bg + 16 * H_ + k0);
    __syncthreads();
    half8 af[4], bf[4];
#pragma unroll
    for (int t = 0; t < 4; ++t)
      af[t] = *(half8*)&As[(wr + t * 16 + l16) * 32 + quad * 8];
#pragma unroll
    for (int t = 0; t < 4; ++t)
      bf[t] = *(half8*)&Bs[(wc + t * 16 + l16) * 32 + quad * 8];
#pragma unroll
    for (int i = 0; i < 4; ++i)
#pragma unroll
      for (int j = 0; j < 4; ++j)
        acc[i][j] = __builtin_amdgcn_mfma_f32_16x16x32_f16(af[i], bf[j],
                                                           acc[i][j], 0, 0, 0);
    __syncthreads();
  }
  // epilogue
#pragma unroll
  for (int i = 0; i < 4; ++i) {
    int r0 = rbase + wr + i * 16 + quad * 4;
    int b = r0 >> 11, sl0 = r0 & (S_ - 1);
    // permuted within-tile offset for the v path (j=r spans the half4)
    int pbase = (sl0 & ~127) + ((sl0 >> 5) & 3) * 32 + ((sl0 >> 2) & 3) * 8 +
                ((sl0 >> 4) & 1) * 4;
#pragma unroll
    for (int j = 0; j < 4; ++j) {
      int col = cbase + wc + j * 16 + l16;
      int h = col >> 6, d = col & 63;
      if (z == 2) {
        half4_t pk;
#pragma unroll
        for (int r = 0; r < 4; ++r) pk[r] = (_Float16)acc[i][j][r];
        *(half4_t*)&vt[((size_t)(b * NH_ + h) * HD_ + d) * S_ + pbase] = pk;
      } else {
        _Float16* outp = (z == 0) ? qh : kh;
        float scale = (z == 0) ? LOG2E : 1.0f;
#pragma unroll
        for (int r = 0; r < 4; ++r) {
          float x = acc[i][j][r];
          x = ((x > 0.f) ? (x + 1.f) : __expf(x)) * scale;
          outp[((size_t)(b * NH_ + h) * S_ + sl0 + r) * HD_ + d] = (_Float16)x;
        }
      }
    }
  }
}

// ---------------- Flash attention ------------------------------------------
// grid (S/128=16, B*NH=32) block 256 (4 waves, 32 q-rows each), BC=128.
// Swapped-operand: QK computes S^T (mfma A=K,B=Q); P^T feeds PV directly
// from registers via 16x16x16 MFMA. V^T is stored key-PERMUTED so each PV
// A-fragment pair is one b128 read (no b64 bank-waste).
__global__ __launch_bounds__(256, 2) void flash_attn(
    const _Float16* __restrict__ qh, const _Float16* __restrict__ kh,
    const _Float16* __restrict__ vt, const int* __restrict__ mask,
    _Float16* __restrict__ attn_out) {
  const int bh = blockIdx.y, b = bh >> 4, h = bh & 15;
  const int qbase = blockIdx.x * 128;
  const int tid = threadIdx.x, w = tid >> 6, lane = tid & 63;
  const int quad = lane >> 4, l16 = lane & 15;

  __shared__ _Float16 Kt[2][128 * 64];  // [key][d], slot = (d>>3)^(key&7)
  __shared__ _Float16 Vt[2][64 * 128];  // [d][pkey], slot = (pchunk)^(d&15)

  const _Float16* Q = qh + (size_t)bh * (S_ * HD_);
  const _Float16* K = kh + (size_t)bh * (S_ * HD_);
  const _Float16* Vg = vt + (size_t)bh * (HD_ * S_);
  const int* Mb = mask + b * S_;

  // Q B-fragments (2 row-groups of 16 q) in registers for the whole kernel
  half8 qf[2][2];
#pragma unroll
  for (int g = 0; g < 2; ++g) {
    int qr = qbase + w * 32 + g * 16 + l16;
    qf[g][0] = *(const half8*)&Q[qr * 64 + quad * 8];
    qf[g][1] = *(const half8*)&Q[qr * 64 + 32 + quad * 8];
  }

  floatx4 zero = {0.f, 0.f, 0.f, 0.f};
  floatx4 o[2][4];  // O^T[d = ct2*16 + quad*4 + r][q = l16 (group g)]
#pragma unroll
  for (int g = 0; g < 2; ++g)
#pragma unroll
    for (int i = 0; i < 4; ++i) o[g][i] = zero;
  float mi[2] = {-3e38f, -3e38f}, li[2] = {0.f, 0.f};

  // staging constants
  const int krow_off = lane >> 3;             // 0..7
  const int kslot = lane & 7;
  const int kchunk = kslot ^ (krow_off & 7);
  const int vrow_off = lane >> 4;             // 0..3
  const int vslot = lane & 15;

  // prologue: stage tile 0 into buffer 0
  {
#pragma unroll
    for (int u = 0; u < 4; ++u) {
      int kl = w * 32 + u * 8;
      async_copy16(&Kt[0][kl * 64], K + (size_t)(kl + krow_off) * 64 + kchunk * 8);
    }
#pragma unroll
    for (int u = 0; u < 4; ++u) {
      int d0 = w * 16 + u * 4 + vrow_off;
      int c0 = vslot ^ (d0 & 15);
      async_copy16(&Vt[0][(w * 16 + u * 4) * 128], Vg + (size_t)d0 * S_ + c0 * 8);
    }
  }

  for (int kt = 0; kt < S_ / 128; ++kt) {
    const int key0 = kt * 128;
    const int buf = kt & 1;
    // barrier: compiler-inserted vmcnt(0) drains our DMA (issued a full tile
    // ago -> latency hidden); barrier makes all waves' DMA visible.
    __syncthreads();
    // prefetch next tile into the other buffer
    if (kt < S_ / 128 - 1) {
      const int key1 = key0 + 128;
#pragma unroll
      for (int u = 0; u < 4; ++u) {
        int kl = w * 32 + u * 8;
        async_copy16(&Kt[buf ^ 1][kl * 64],
                     K + (size_t)(key1 + kl + krow_off) * 64 + kchunk * 8);
      }
#pragma unroll
      for (int u = 0; u < 4; ++u) {
        int d0 = w * 16 + u * 4 + vrow_off;
        int c0 = vslot ^ (d0 & 15);
        async_copy16(&Vt[buf ^ 1][(w * 16 + u * 4) * 128],
                     Vg + (size_t)d0 * S_ + key1 + c0 * 8);
      }
    }
    int m0 = Mb[key0 + lane];
    int m1 = Mb[key0 + 64 + lane];

    const _Float16* Kb = &Kt[buf][0];
    const _Float16* Vb = &Vt[buf][0];

    // S^T tile: mfma(A=K-frag, B=Q-frag) -> S^T[key=ct*16+quad*4+r][q=l16]
    floatx4 sa[2][8];
#pragma unroll
    for (int g = 0; g < 2; ++g)
#pragma unroll
      for (int ct = 0; ct < 8; ++ct) sa[g][ct] = zero;
    {
      int s0 = quad ^ (l16 & 7);
      int s1 = (4 + quad) ^ (l16 & 7);
#pragma unroll
      for (int ct = 0; ct < 8; ++ct) {
        int key = ct * 16 + l16;
        half8 bf0 = *(half8*)&Kb[key * 64 + s0 * 8];
        half8 bf1 = *(half8*)&Kb[key * 64 + s1 * 8];
        sa[0][ct] = __builtin_amdgcn_mfma_f32_16x16x32_f16(bf0, qf[0][0], sa[0][ct], 0, 0, 0);
        sa[0][ct] = __builtin_amdgcn_mfma_f32_16x16x32_f16(bf1, qf[0][1], sa[0][ct], 0, 0, 0);
        sa[1][ct] = __builtin_amdgcn_mfma_f32_16x16x32_f16(bf0, qf[1][0], sa[1][ct], 0, 0, 0);
        sa[1][ct] = __builtin_amdgcn_mfma_f32_16x16x32_f16(bf1, qf[1][1], sa[1][ct], 0, 0, 0);
      }
    }
    // masking (fast path: tile fully unmasked). key = ct*16 + quad*4 + r
    if (__any((m0 == 0) || (m1 == 0))) {
#pragma unroll
      for (int ct = 0; ct < 8; ++ct)
#pragma unroll
        for (int r = 0; r < 4; ++r)
          if (Mb[key0 + ct * 16 + quad * 4 + r] == 0) {
            sa[0][ct][r] = -1e30f;
            sa[1][ct][r] = -1e30f;
          }
    }
    // online softmax per q-column (in-lane over 32 logits + 2 shuffles)
#pragma unroll
    for (int g = 0; g < 2; ++g) {
      float mx = sa[g][0][0];
#pragma unroll
      for (int ct = 0; ct < 8; ++ct)
#pragma unroll
        for (int r = 0; r < 4; ++r) mx = fmaxf(mx, sa[g][ct][r]);
      mx = fmaxf(mx, __shfl_xor(mx, 16));
      mx = fmaxf(mx, __shfl_xor(mx, 32));
      float mn = fmaxf(mi[g], mx);
      float alpha = __builtin_amdgcn_exp2f(mi[g] - mn);
      mi[g] = mn;
      float rs = 0.f;
#pragma unroll
      for (int ct = 0; ct < 8; ++ct)
#pragma unroll
        for (int r = 0; r < 4; ++r) {
          float p = __builtin_amdgcn_exp2f(sa[g][ct][r] - mn);
          sa[g][ct][r] = p;
          rs += p;
        }
      rs += __shfl_xor(rs, 16);
      rs += __shfl_xor(rs, 32);
      li[g] = li[g] * alpha + rs;
#pragma unroll
      for (int ct2 = 0; ct2 < 4; ++ct2) {
        o[g][ct2][0] *= alpha; o[g][ct2][1] *= alpha;
        o[g][ct2][2] *= alpha; o[g][ct2][3] *= alpha;
      }
    }
    // PV: O^T += mfma(A=V^T-frag, B=P^T-frag), ct-pairs share one b128 read.
    // Permuted V storage: chunk (4t+quad)^ (d&15) holds keys
    // {32t+quad*4..+3} (low half) and {32t+16+quad*4..+3} (high half).
#pragma unroll
    for (int t = 0; t < 4; ++t) {
      half4_t p0a, p0b, p1a, p1b;
#pragma unroll
      for (int r = 0; r < 4; ++r) {
        p0a[r] = (_Float16)sa[0][2 * t][r];
        p1a[r] = (_Float16)sa[1][2 * t][r];
        p0b[r] = (_Float16)sa[0][2 * t + 1][r];
        p1b[r] = (_Float16)sa[1][2 * t + 1][r];
      }
#pragma unroll
      for (int ct2 = 0; ct2 < 4; ++ct2) {
        int d = ct2 * 16 + l16;
        int slot = (4 * t + quad) ^ l16;
        half8 vf8 = *(half8*)&Vb[d * 128 + slot * 8];
        half4_t vlo = {vf8[0], vf8[1], vf8[2], vf8[3]};
        half4_t vhi = {vf8[4], vf8[5], vf8[6], vf8[7]};
        o[0][ct2] = __builtin_amdgcn_mfma_f32_16x16x16f16(vlo, p0a, o[0][ct2], 0, 0, 0);
        o[1][ct2] = __builtin_amdgcn_mfma_f32_16x16x16f16(vlo, p1a, o[1][ct2], 0, 0, 0);
        o[0][ct2] = __builtin_amdgcn_mfma_f32_16x16x16f16(vhi, p0b, o[0][ct2], 0, 0, 0);
        o[1][ct2] = __builtin_amdgcn_mfma_f32_16x16x16f16(vhi, p1b, o[1][ct2], 0, 0, 0);
      }
    }
  }
  // epilogue: normalize, store (B, S, H) fp16 — half4 stores (d contiguous)
#pragma unroll
  for (int g = 0; g < 2; ++g) {
    float inv = 1.0f / li[g];
    int row = qbase + w * 32 + g * 16 + l16;
#pragma unroll
    for (int ct2 = 0; ct2 < 4; ++ct2) {
      half4_t pk;
#pragma unroll
      for (int r = 0; r < 4; ++r) pk[r] = (_Float16)(o[g][ct2][r] * inv);
      int d = ct2 * 16 + quad * 4;
      *(half4_t*)&attn_out[((size_t)(b * S_ + row)) * H_ + h * HD_ + d] = pk;
    }
  }
}

// ---------------- Output GEMM: out = AO @ Wo^T (fp32 out) ------------------
// grid (16, 32) block 256: 128x64 tiles -> 512 blocks (2/CU)
__global__ __launch_bounds__(256) void out_gemm(
    const _Float16* __restrict__ A, const _Float16* __restrict__ W,
    float* __restrict__ out) {
  const int rbase = blockIdx.y * 128;
  const int cbase = blockIdx.x * 64;
  __shared__ _Float16 As[128 * 32];
  __shared__ _Float16 Bs[64 * 32];
  const int tid = threadIdx.x, lane = tid & 63, w = tid >> 6;
  const int quad = lane >> 4, l16 = lane & 15;

  floatx4 zero = {0.f, 0.f, 0.f, 0.f};
  floatx4 acc[2][4];
#pragma unroll
  for (int i = 0; i < 2; ++i)
#pragma unroll
    for (int j = 0; j < 4; ++j) acc[i][j] = zero;

  const int srowA = w * 32 + (lane >> 2);
  const int srowB = w * 16 + (lane >> 2);
  const int sseg = (lane & 3) * 8;
  const _Float16* Ag = A + (size_t)(rbase + srowA) * H_ + sseg;
  const _Float16* Bg = W + (size_t)(cbase + srowB) * H_ + sseg;

  for (int k0 = 0; k0 < H_; k0 += 32) {
    async_copy16(&As[(w * 32) * 32], Ag + k0);
    async_copy16(&As[(w * 32 + 16) * 32], Ag + 16 * H_ + k0);
    async_copy16(&Bs[(w * 16) * 32], Bg + k0);
    __syncthreads();
    half8 af[2], bf[4];
#pragma unroll
    for (int t = 0; t < 2; ++t)
      af[t] = *(half8*)&As[(w * 32 + t * 16 + l16) * 32 + quad * 8];
#pragma unroll
    for (int t = 0; t < 4; ++t)
      bf[t] = *(half8*)&Bs[(t * 16 + l16) * 32 + quad * 8];
#pragma unroll
    for (int i = 0; i < 2; ++i)
#pragma unroll
      for (int j = 0; j < 4; ++j)
        acc[i][j] = __builtin_amdgcn_mfma_f32_16x16x32_f16(af[i], bf[j],
                                                           acc[i][j], 0, 0, 0);
    __syncthreads();
  }
#pragma unroll
  for (int i = 0; i < 2; ++i) {
    int r0 = rbase + w * 32 + i * 16 + quad * 4;
#pragma unroll
    for (int j = 0; j < 4; ++j) {
      int col = cbase + j * 16 + l16;
#pragma unroll
      for (int r = 0; r < 4; ++r)
        out[(size_t)(r0 + r) * H_ + col] = acc[i][j][r];
    }
  }
}

extern "C" void kernel_launch(void* const* d_in, const int* in_sizes, int n_in,
                              void* d_out, int out_size, void* d_ws,
                              size_t ws_size, hipStream_t stream) {
  const float* hs = (const float*)d_in[0];
  const int* mask = (const int*)d_in[1];
  const float* Wq = (const float*)d_in[2];
  const float* Wk = (const float*)d_in[3];
  const float* Wv = (const float*)d_in[4];
  const float* Wo = (const float*)d_in[5];
  float* out = (float*)d_out;

  _Float16* p = (_Float16*)d_ws;
  _Float16* hs_h = p; p += (size_t)BS_ * H_;
  _Float16* w_h = p;  p += (size_t)4 * H_ * H_;
  _Float16* q_h = p;  p += (size_t)BS_ * H_;
  _Float16* k_h = p;  p += (size_t)BS_ * H_;
  _Float16* v_t = p;  p += (size_t)BS_ * H_;
  _Float16* ao_h = p; p += (size_t)BS_ * H_;

  cvt_all<<<8192, 256, 0, stream>>>(hs, Wq, Wk, Wv, Wo, hs_h, w_h);
  qkv_gemm<<<dim3(8, 32, 3), 256, 0, stream>>>(hs_h, w_h, q_h, k_h, v_t);
  flash_attn<<<dim3(16, 32), 256, 0, stream>>>(q_h, k_h, v_t, mask, ao_h);
  out_gemm<<<dim3(16, 32), 256, 0, stream>>>(ao_h, w_h + (size_t)3 * H_ * H_, out);
}